// Round 13
// baseline (1370.250 us; speedup 1.0000x reference)
//
#include <hip/hip_runtime.h>
#include <hip/hip_cooperative_groups.h>

// CKY inside-outside, B=16, S=192 — ONE persistent cooperative kernel.
// 192 blocks (= BB*NTL) x 256 threads, co-resident; grid.sync() replaces the
// 25 per-diagonal kernel launches of R12 (each cost ~25-50us fixed overhead).
// Per diagonal: block = (batch, tile I). interior = thread-per-cell LSE over
// completed tiles (global float4 rows + transposes); chain = wave 0 resolves
// the 31 in-tile sub-diagonals in private LDS with DPP quad merges.

namespace cg = cooperative_groups;

#define SS 192
#define BB 16
#define TT 16
#define NTL 12
#define NBLK (BB * NTL)
#define NEGF (-1e30f)

__device__ __forceinline__ float softplusf(float x) {
  return fmaxf(x, 0.f) + log1pf(__expf(-fabsf(x)));
}
__device__ __forceinline__ void lse_merge(float& m, float& s, float m2, float s2) {
  float nm = fmaxf(m, m2);
  s = s * __expf(m - nm) + s2 * __expf(m2 - nm);
  m = nm;
}
template <int CTRL>
__device__ __forceinline__ float dppf(float x) {   // quad_perm cross-lane (VALU)
  return __int_as_float(__builtin_amdgcn_update_dpp(
      0, __float_as_int(x), CTRL, 0xF, 0xF, true));
}
// 0xB1 = quad_perm xor1, 0x4E = quad_perm xor2

__global__ __launch_bounds__(256) void cky_all(const float* __restrict__ rules,
                                               const int* __restrict__ lens,
                                               float* __restrict__ chGb,
                                               float* __restrict__ chTGb,
                                               float* __restrict__ odGb,
                                               float* __restrict__ odTGb,
                                               float* __restrict__ outZ,
                                               float* __restrict__ marg) {
  cg::grid_group grid = cg::this_grid();
  const int bid = blockIdx.x;
  const int tid = threadIdx.x;
  const int ci = tid >> 4, cj = tid & 15;

  __shared__ float A[TT][TT + 1], Bt[TT][TT + 1], T[TT][TT + 1];
  __shared__ float P[TT][TT + 1], SP[TT][TT + 1];
  __shared__ float brow[TT];

  // ---------------- phase 0: NEG-init odG/odTG ----------------
  {
    const int n4 = BB * SS * SS / 4;
    float4 nf = make_float4(NEGF, NEGF, NEGF, NEGF);
    float4* a = reinterpret_cast<float4*>(odGb);
    float4* c = reinterpret_cast<float4*>(odTGb);
    for (int i = bid * 256 + tid; i < n4; i += NBLK * 256) { a[i] = nf; c[i] = nf; }
  }
  grid.sync();

  // ---------------- INSIDE: tile-diagonals ascending ----------------
  for (int d = 0; d < NTL; ++d) {
    const int ntiles = NTL - d;
    if (bid < BB * ntiles) {
      const int b = bid / ntiles;
      const int I = bid % ntiles;
      const int J = I + d;
      const int gi = TT * I + ci, gj = TT * J + cj;
      const float* __restrict__ R = rules + (size_t)b * SS * SS;
      float* __restrict__ chG  = chGb  + (size_t)b * SS * SS;
      float* __restrict__ chTG = chTGb + (size_t)b * SS * SS;

      const float spv_own = softplusf(R[gi * SS + gj]);
      SP[ci][cj] = spv_own;
      T[ci][cj] = (d == 0 && ci == cj) ? spv_own : NEGF;
      if (d >= 1) {
        A[ci][cj]  = chG[(TT * I + ci) * SS + TT * I + cj];
        Bt[ci][cj] = chG[(TT * J + ci) * SS + TT * J + cj];
      }
      if (d >= 2 && tid < TT) brow[tid] = chG[(TT * (I + 1)) * SS + TT * J + tid];

      // interior partial over k in [16(I+1), 16J)
      {
        float m = NEGF, s = 0.f;
        const float* chRow  = chG  + gi * SS;
        const float* chTRow = chTG + gj * SS;
        const int k0 = TT * (I + 1), k1 = TT * J;
        if (k0 < k1) {
          float4 blo = *reinterpret_cast<const float4*>(chTRow + k0);
          for (int k = k0; k < k1; k += 4) {
            float4 a4  = *reinterpret_cast<const float4*>(chRow + k);
            float4 bhi = *reinterpret_cast<const float4*>(chTRow + k + 4);
            float v0 = a4.x + blo.y, v1 = a4.y + blo.z;
            float v2 = a4.z + blo.w, v3 = a4.w + bhi.x;
            float bm = fmaxf(fmaxf(v0, v1), fmaxf(v2, v3));
            float bs = __expf(v0 - bm) + __expf(v1 - bm) +
                       __expf(v2 - bm) + __expf(v3 - bm);
            lse_merge(m, s, bm, bs);
            blo = bhi;
          }
        }
        P[ci][cj] = (m < -1e29f) ? NEGF : m + __logf(s);
      }
      __syncthreads();

      // chain: wave 0, private LDS
      if (tid < 64) {
        const int cidx = tid >> 2, g = tid & 3;
        const int s0 = (d == 0) ? TT : 0;
        for (int st = s0; st <= 30; ++st) {
          int ilmin = 15 - st; if (ilmin < 0) ilmin = 0;
          int ilmax = 30 - st; if (ilmax > 15) ilmax = 15;
          bool act = (cidx <= ilmax - ilmin);
          int tci = ilmin + (act ? cidx : 0);
          int tcj = tci + st - 15;
          int c1 = (d == 0) ? (st - 15) : (TT - tci);
          int c2 = (d == 0) ? 0 : tcj;
          int nt = c1 + c2;
          float m  = (g == 0) ? P[tci][tcj] : NEGF;
          float sa = (g == 0) ? 1.f : 0.f;
          float tv[8];
          #pragma unroll
          for (int u = 0; u < 8; ++u) {
            int t = g + 4 * u;
            bool ok = act && (t < nt);
            int tc = ok ? t : 0;
            float va, vb;
            if (tc < c1) {
              int kk = tci + tc;
              va = (d == 0) ? T[tci][kk] : A[tci][kk];
              int r2 = kk + 1;
              if (r2 <= 15) vb = T[r2][tcj];
              else          vb = (d == 1) ? Bt[0][tcj] : brow[tcj];
            } else {
              int tp = tc - c1;
              va = T[tci][tp];
              vb = Bt[tp + 1][tcj];
            }
            tv[u] = ok ? (va + vb) : NEGF;
          }
          float m0 = fmaxf(tv[0], tv[1]), m1 = fmaxf(tv[2], tv[3]);
          float m2 = fmaxf(tv[4], tv[5]), m3 = fmaxf(tv[6], tv[7]);
          float bm = fmaxf(fmaxf(m0, m1), fmaxf(m2, m3));
          float bs = (__expf(tv[0] - bm) + __expf(tv[1] - bm)) +
                     (__expf(tv[2] - bm) + __expf(tv[3] - bm)) +
                     (__expf(tv[4] - bm) + __expf(tv[5] - bm)) +
                     (__expf(tv[6] - bm) + __expf(tv[7] - bm));
          lse_merge(m, sa, bm, bs);
          lse_merge(m, sa, dppf<0xB1>(m), dppf<0xB1>(sa));
          lse_merge(m, sa, dppf<0x4E>(m), dppf<0x4E>(sa));
          if (act && g == 0)
            T[tci][tcj] = SP[tci][tcj] + m + __logf(sa);
          __builtin_amdgcn_wave_barrier();
        }
      }
      __syncthreads();
      chG [gi * SS + gj] = T[ci][cj];
      chTG[gj * SS + gi] = T[ci][cj];
    }
    grid.sync();
  }

  // ---------------- OUTSIDE: tile-diagonals descending ----------------
  for (int d = NTL - 1; d >= 0; --d) {
    const int ntiles = NTL - d;
    if (bid < BB * ntiles) {
      const int b = bid / ntiles;
      const int I = bid % ntiles;
      const int J = I + d;
      const int L = lens[b];
      if (TT * J < L) {                          // skip-guard (no return!)
        const int gi = TT * I + ci, gj = TT * J + cj;
        const float* __restrict__ R = rules + (size_t)b * SS * SS;
        const float* __restrict__ chG  = chGb  + (size_t)b * SS * SS;
        const float* __restrict__ chTG = chTGb + (size_t)b * SS * SS;
        float* __restrict__ odG  = odGb  + (size_t)b * SS * SS;
        float* __restrict__ odTG = odTGb + (size_t)b * SS * SS;

        const float spv_own = softplusf(R[gi * SS + gj]);
        SP[ci][cj] = spv_own;
        A[ci][cj]  = chG[(TT * I + ci) * SS + TT * I + cj];
        Bt[ci][cj] = chG[(TT * J + ci) * SS + TT * J + cj];
        const bool isroot = (gi == 0) && (gj == L - 1);
        T[ci][cj] = isroot ? spv_own : NEGF;

        {
          float m = NEGF, s = 0.f;
          const float* odRow   = odG + gi * SS;
          const float* chRowJ1 = chG + (gj + 1) * SS;
          const int p0 = TT * (J + 1);
          for (int p = p0; p < SS; p += 4) {
            float4 o4 = *reinterpret_cast<const float4*>(odRow + p);
            float4 c4 = *reinterpret_cast<const float4*>(chRowJ1 + p);
            float v0 = o4.x + c4.x, v1 = o4.y + c4.y;
            float v2 = o4.z + c4.z, v3 = o4.w + c4.w;
            float bm = fmaxf(fmaxf(v0, v1), fmaxf(v2, v3));
            float bs = __expf(v0 - bm) + __expf(v1 - bm) +
                       __expf(v2 - bm) + __expf(v3 - bm);
            lse_merge(m, s, bm, bs);
          }
          const float* odTRow   = odTG + gj * SS;
          const float* chTRowI1 = chTG + (gi - 1) * SS;
          const int aEnd = TT * I;
          for (int a = 0; a < aEnd; a += 4) {
            float4 o4 = *reinterpret_cast<const float4*>(odTRow + a);
            float4 c4 = *reinterpret_cast<const float4*>(chTRowI1 + a);
            float v0 = o4.x + c4.x, v1 = o4.y + c4.y;
            float v2 = o4.z + c4.z, v3 = o4.w + c4.w;
            float bm = fmaxf(fmaxf(v0, v1), fmaxf(v2, v3));
            float bs = __expf(v0 - bm) + __expf(v1 - bm) +
                       __expf(v2 - bm) + __expf(v3 - bm);
            lse_merge(m, s, bm, bs);
          }
          P[ci][cj] = (m < -1e29f) ? NEGF : m + __logf(s);
        }
        __syncthreads();

        if (tid < 64) {
          const int cidx = tid >> 2, g = tid & 3;
          const int sEnd = (d == 0) ? 15 : 0;
          for (int st = 30; st >= sEnd; --st) {
            int ilmin = 15 - st; if (ilmin < 0) ilmin = 0;
            int ilmax = 30 - st; if (ilmax > 15) ilmax = 15;
            bool act = (cidx <= ilmax - ilmin);
            int tci = ilmin + (act ? cidx : 0);
            int tcj = tci + st - 15;
            int tgi = TT * I + tci, tgj = TT * J + tcj;
            bool rooted = (tgi == 0 && tgj == L - 1);
            bool dowrite = act && (tgj < L) && !rooted;
            int c1 = 15 - tcj, c2 = tci;
            int nt = c1 + c2;
            float m  = (g == 0) ? P[tci][tcj] : NEGF;
            float sa = (g == 0) ? 1.f : 0.f;
            int cim1 = (tci > 0) ? tci - 1 : 0;
            float tv[8];
            #pragma unroll
            for (int u = 0; u < 8; ++u) {
              int t = g + 4 * u;
              bool ok = act && (t < nt);
              int tc = ok ? t : 0;
              float va, vb;
              if (tc < c1) {
                int pl = tcj + 1 + tc;
                va = T[tci][pl];
                vb = Bt[tcj + 1][pl];
              } else {
                int al = tc - c1;
                va = T[al][tcj];
                vb = A[al][cim1];
              }
              tv[u] = ok ? (va + vb) : NEGF;
            }
            float m0 = fmaxf(tv[0], tv[1]), m1 = fmaxf(tv[2], tv[3]);
            float m2 = fmaxf(tv[4], tv[5]), m3 = fmaxf(tv[6], tv[7]);
            float bm = fmaxf(fmaxf(m0, m1), fmaxf(m2, m3));
            float bs = (__expf(tv[0] - bm) + __expf(tv[1] - bm)) +
                       (__expf(tv[2] - bm) + __expf(tv[3] - bm)) +
                       (__expf(tv[4] - bm) + __expf(tv[5] - bm)) +
                       (__expf(tv[6] - bm) + __expf(tv[7] - bm));
            lse_merge(m, sa, bm, bs);
            lse_merge(m, sa, dppf<0xB1>(m), dppf<0xB1>(sa));
            lse_merge(m, sa, dppf<0x4E>(m), dppf<0x4E>(sa));
            if (dowrite && g == 0)
              T[tci][tcj] = SP[tci][tcj] + m + __logf(sa);
            __builtin_amdgcn_wave_barrier();
          }
        }
        __syncthreads();
        odG [gi * SS + gj] = T[ci][cj];
        odTG[gj * SS + gi] = T[ci][cj];
      }
    }
    grid.sync();
  }

  // ---------------- marginals + Z ----------------
  {
    const int total = BB * SS * SS;
    for (int idx = bid * 256 + tid; idx < total; idx += NBLK * 256) {
      int b = idx / (SS * SS);
      int rem = idx - b * SS * SS;
      int i = rem / SS, j = rem - i * SS;
      int L = lens[b];
      if (rem == 0) outZ[b] = chGb[(size_t)b * SS * SS + (L - 1)];
      float val = 0.f;
      if (i <= j && j < L) {
        float r = rules[idx];
        float sp = softplusf(r);
        float Z = chGb[(size_t)b * SS * SS + (L - 1)];
        float o = odGb[idx] - sp;
        float c = chGb[idx];
        float sig = 1.f / (1.f + __expf(-r));
        val = sig * __expf(o + c - Z);
      }
      marg[idx] = val;
    }
  }
}

extern "C" void kernel_launch(void* const* d_in, const int* in_sizes, int n_in,
                              void* d_out, int out_size, void* d_ws, size_t ws_size,
                              hipStream_t stream) {
  const float* rules = (const float*)d_in[0];   // (B,S,S,1) f32
  const int* lens = (const int*)d_in[1];        // (B,) i32
  float* outZ = (float*)d_out;                  // [0:16) = Z
  float* marg = (float*)d_out + BB;             // [16:) = marginal

  float* chG_  = (float*)d_ws;                          // B*S*S
  float* chTG_ = chG_  + (size_t)BB * SS * SS;          // B*S*S
  float* odG_  = chTG_ + (size_t)BB * SS * SS;          // B*S*S
  float* odTG_ = odG_  + (size_t)BB * SS * SS;          // B*S*S

  void* args[] = {(void*)&rules, (void*)&lens, (void*)&chG_, (void*)&chTG_,
                  (void*)&odG_, (void*)&odTG_, (void*)&outZ, (void*)&marg};
  hipLaunchCooperativeKernel(reinterpret_cast<void*>(cky_all),
                             dim3(NBLK), dim3(256), args, 0, stream);
}